// Round 1
// baseline (378.705 us; speedup 1.0000x reference)
//
#include <hip/hip_runtime.h>

#define S_LEN 2048
#define D_MODEL 1024
#define NHEAD 16
#define HDIM 64
#define BATCH 2
#define M_ROWS (BATCH * S_LEN)   // 4096
#define N_QKV (3 * D_MODEL)      // 3072

typedef __attribute__((ext_vector_type(8))) short bf16x8;
typedef __attribute__((ext_vector_type(4))) float f32x4;

static __device__ __forceinline__ unsigned short f2bf(float f) {
  unsigned int u = __float_as_uint(f);
  u += 0x7FFFu + ((u >> 16) & 1u);   // RNE
  return (unsigned short)(u >> 16);
}
static __device__ __forceinline__ float bf2f(unsigned short h) {
  return __uint_as_float(((unsigned int)h) << 16);
}

// ---------------- cast fp32 -> bf16 (vectorized x4) ----------------
__global__ __launch_bounds__(256) void k_cast4(const float* __restrict__ x,
                                               unsigned short* __restrict__ y, int n4) {
  int i = blockIdx.x * 256 + threadIdx.x;
  if (i >= n4) return;
  float4 v = ((const float4*)x)[i];
  ushort4 o;
  o.x = f2bf(v.x); o.y = f2bf(v.y); o.z = f2bf(v.z); o.w = f2bf(v.w);
  ((ushort4*)y)[i] = o;
}

// ------------- transpose + cast: w[K][N] fp32 -> wT[N][K] bf16 -------------
__global__ __launch_bounds__(256) void k_transcast(const float* __restrict__ w,
                                                   unsigned short* __restrict__ wT,
                                                   int Kdim, int Ndim) {
  __shared__ unsigned short T[32][33];
  int n0 = blockIdx.x * 32, k0 = blockIdx.y * 32;
  int tx = threadIdx.x & 31, ty = threadIdx.x >> 5;
#pragma unroll
  for (int j = 0; j < 4; ++j) {
    int r = ty + j * 8;
    T[r][tx] = f2bf(w[(size_t)(k0 + r) * Ndim + n0 + tx]);
  }
  __syncthreads();
#pragma unroll
  for (int j = 0; j < 4; ++j) {
    int r = ty + j * 8;
    wT[(size_t)(n0 + r) * Kdim + k0 + tx] = T[tx][r];
  }
}

// ---------------- QKV GEMM: [4096,1024] x [1024,3072] + bias ----------------
// A row-major bf16, Bt = W^T [N][K] bf16. 128x128 tile, BK=32, 4 waves (2x2 of 64x64).
__global__ __launch_bounds__(256) void k_gemm_qkv(const unsigned short* __restrict__ A,
                                                  const unsigned short* __restrict__ Bt,
                                                  const float* __restrict__ bias,
                                                  unsigned short* __restrict__ Qb,
                                                  unsigned short* __restrict__ Kb,
                                                  unsigned short* __restrict__ Vb) {
  __shared__ __align__(16) unsigned short As[128 * 32];
  __shared__ __align__(16) unsigned short Bs[128 * 32];
  const int tid = threadIdx.x;
  const int wid = tid >> 6, lane = tid & 63;
  const int lr = lane & 15, lg = lane >> 4;
  const int bm = blockIdx.y * 128, bn = blockIdx.x * 128;
  const int wm = (wid >> 1) * 64, wn = (wid & 1) * 64;
  const int K = D_MODEL;
  const int c0 = tid, c1 = tid + 256;   // 16B chunks: row = c>>2, kchunk = c&3
  const size_t a0o = (size_t)(bm + (c0 >> 2)) * K + (c0 & 3) * 8;
  const size_t a1o = (size_t)(bm + (c1 >> 2)) * K + (c1 & 3) * 8;
  const size_t b0o = (size_t)(bn + (c0 >> 2)) * K + (c0 & 3) * 8;
  const size_t b1o = (size_t)(bn + (c1 >> 2)) * K + (c1 & 3) * 8;

  f32x4 acc[4][4] = {};

  for (int k0 = 0; k0 < K; k0 += 32) {
    uint4 a0 = *(const uint4*)&A[a0o + k0];
    uint4 a1 = *(const uint4*)&A[a1o + k0];
    uint4 b0 = *(const uint4*)&Bt[b0o + k0];
    uint4 b1 = *(const uint4*)&Bt[b1o + k0];
    __syncthreads();
    *(uint4*)&As[c0 * 8] = a0;
    *(uint4*)&As[c1 * 8] = a1;
    *(uint4*)&Bs[c0 * 8] = b0;
    *(uint4*)&Bs[c1 * 8] = b1;
    __syncthreads();
    bf16x8 af[4], bfr[4];
#pragma unroll
    for (int i = 0; i < 4; ++i) af[i] = *(const bf16x8*)&As[(wm + i * 16 + lr) * 32 + lg * 8];
#pragma unroll
    for (int t = 0; t < 4; ++t) bfr[t] = *(const bf16x8*)&Bs[(wn + t * 16 + lr) * 32 + lg * 8];
#pragma unroll
    for (int i = 0; i < 4; ++i)
#pragma unroll
      for (int t = 0; t < 4; ++t)
        acc[i][t] = __builtin_amdgcn_mfma_f32_16x16x32_bf16(af[i], bfr[t], acc[i][t], 0, 0, 0);
  }
  // epilogue: scatter into Q/K/V [B,H,S,hd] bf16 with bias
#pragma unroll
  for (int i = 0; i < 4; ++i) {
#pragma unroll
    for (int t = 0; t < 4; ++t) {
      int n = bn + wn + t * 16 + lr;
      int part = n >> 10, rem = n & 1023;
      int h = rem >> 6, d = rem & 63;
      unsigned short* dst = part == 0 ? Qb : (part == 1 ? Kb : Vb);
      float bv = bias[n];
#pragma unroll
      for (int r = 0; r < 4; ++r) {
        int row = bm + wm + i * 16 + lg * 4 + r;      // = b*2048 + s
        int b = row >> 11, s = row & 2047;
        dst[((size_t)((b << 4) + h) * S_LEN + s) * HDIM + d] = f2bf(acc[i][t][r] + bv);
      }
    }
  }
}

// ---------------- Proj GEMM: [4096,1024] x [1024,1024] + bias -> fp32 ----------------
__global__ __launch_bounds__(256) void k_gemm_proj(const unsigned short* __restrict__ A,
                                                   const unsigned short* __restrict__ Bt,
                                                   const float* __restrict__ bias,
                                                   float* __restrict__ out) {
  __shared__ __align__(16) unsigned short As[128 * 32];
  __shared__ __align__(16) unsigned short Bs[128 * 32];
  const int tid = threadIdx.x;
  const int wid = tid >> 6, lane = tid & 63;
  const int lr = lane & 15, lg = lane >> 4;
  const int bm = blockIdx.y * 128, bn = blockIdx.x * 128;
  const int wm = (wid >> 1) * 64, wn = (wid & 1) * 64;
  const int K = D_MODEL;
  const int c0 = tid, c1 = tid + 256;
  const size_t a0o = (size_t)(bm + (c0 >> 2)) * K + (c0 & 3) * 8;
  const size_t a1o = (size_t)(bm + (c1 >> 2)) * K + (c1 & 3) * 8;
  const size_t b0o = (size_t)(bn + (c0 >> 2)) * K + (c0 & 3) * 8;
  const size_t b1o = (size_t)(bn + (c1 >> 2)) * K + (c1 & 3) * 8;

  f32x4 acc[4][4] = {};

  for (int k0 = 0; k0 < K; k0 += 32) {
    uint4 a0 = *(const uint4*)&A[a0o + k0];
    uint4 a1 = *(const uint4*)&A[a1o + k0];
    uint4 b0 = *(const uint4*)&Bt[b0o + k0];
    uint4 b1 = *(const uint4*)&Bt[b1o + k0];
    __syncthreads();
    *(uint4*)&As[c0 * 8] = a0;
    *(uint4*)&As[c1 * 8] = a1;
    *(uint4*)&Bs[c0 * 8] = b0;
    *(uint4*)&Bs[c1 * 8] = b1;
    __syncthreads();
    bf16x8 af[4], bfr[4];
#pragma unroll
    for (int i = 0; i < 4; ++i) af[i] = *(const bf16x8*)&As[(wm + i * 16 + lr) * 32 + lg * 8];
#pragma unroll
    for (int t = 0; t < 4; ++t) bfr[t] = *(const bf16x8*)&Bs[(wn + t * 16 + lr) * 32 + lg * 8];
#pragma unroll
    for (int i = 0; i < 4; ++i)
#pragma unroll
      for (int t = 0; t < 4; ++t)
        acc[i][t] = __builtin_amdgcn_mfma_f32_16x16x32_bf16(af[i], bfr[t], acc[i][t], 0, 0, 0);
  }
#pragma unroll
  for (int i = 0; i < 4; ++i) {
#pragma unroll
    for (int t = 0; t < 4; ++t) {
      int n = bn + wn + t * 16 + lr;
      float bv = bias[n];
#pragma unroll
      for (int r = 0; r < 4; ++r) {
        int row = bm + wm + i * 16 + lg * 4 + r;
        out[(size_t)row * D_MODEL + n] = acc[i][t][r] + bv;
      }
    }
  }
}

// ---------------- Flash attention (causal), 1 block = (bh, 64-row Q tile) ----------------
__global__ __launch_bounds__(256) void k_attn(const unsigned short* __restrict__ Qb,
                                              const unsigned short* __restrict__ Kb,
                                              const unsigned short* __restrict__ Vb,
                                              unsigned short* __restrict__ AO) {
  const int qt = blockIdx.x;   // 0..31
  const int bh = blockIdx.y;   // b*16+h
  const int tid = threadIdx.x;
  const int wid = tid >> 6, lane = tid & 63;
  const int lr = lane & 15, lg = lane >> 4;
  const int b = bh >> 4, h = bh & 15;

  __shared__ __align__(16) unsigned short Qs[64 * 64];
  __shared__ __align__(16) unsigned short Ks[64 * 64];
  __shared__ __align__(16) unsigned short VTs[64 * 72];  // V^T, pad 72 (144B rows, 16B aligned)
  __shared__ __align__(16) unsigned short Ps[64 * 64];

  const unsigned short* Qp = Qb + ((size_t)bh * S_LEN + qt * 64) * HDIM;
  ((uint4*)Qs)[tid] = ((const uint4*)Qp)[tid];
  ((uint4*)Qs)[tid + 256] = ((const uint4*)Qp)[tid + 256];

  f32x4 O[4] = {};
  float m_i[4], l_i[4];
#pragma unroll
  for (int r = 0; r < 4; ++r) { m_i[r] = -1e30f; l_i[r] = 0.f; }

  const int row_base = qt * 64 + wid * 16 + lg * 4;

  for (int kt = 0; kt <= qt; ++kt) {
    const unsigned short* Kp = Kb + ((size_t)bh * S_LEN + kt * 64) * HDIM;
    const unsigned short* Vp = Vb + ((size_t)bh * S_LEN + kt * 64) * HDIM;
    ((uint4*)Ks)[tid] = ((const uint4*)Kp)[tid];
    ((uint4*)Ks)[tid + 256] = ((const uint4*)Kp)[tid + 256];
#pragma unroll
    for (int ii = 0; ii < 16; ++ii) {
      int idx = ii * 256 + tid;
      int key = idx >> 6, d = idx & 63;
      VTs[d * 72 + key] = Vp[idx];
    }
    __syncthreads();

    // S strip = Q(16 rows) @ K^T (64 cols)
    f32x4 Sv[4];
#pragma unroll
    for (int t = 0; t < 4; ++t) {
      f32x4 a = {};
#pragma unroll
      for (int ks = 0; ks < 2; ++ks) {
        bf16x8 qa = *(const bf16x8*)&Qs[(wid * 16 + lr) * 64 + ks * 32 + lg * 8];
        bf16x8 kf = *(const bf16x8*)&Ks[(t * 16 + lr) * 64 + ks * 32 + lg * 8];
        a = __builtin_amdgcn_mfma_f32_16x16x32_bf16(qa, kf, a, 0, 0, 0);
      }
      Sv[t] = a;
    }

    const int col_base = kt * 64;
#pragma unroll
    for (int r = 0; r < 4; ++r) {
      int row_g = row_base + r;
      float mx = -1e30f;
#pragma unroll
      for (int t = 0; t < 4; ++t) {
        int col = col_base + t * 16 + lr;
        float s = Sv[t][r] * 0.125f;     // 1/sqrt(64)
        if (col > row_g) s = -1e30f;     // causal mask
        Sv[t][r] = s;
        mx = fmaxf(mx, s);
      }
      mx = fmaxf(mx, __shfl_xor(mx, 1));
      mx = fmaxf(mx, __shfl_xor(mx, 2));
      mx = fmaxf(mx, __shfl_xor(mx, 4));
      mx = fmaxf(mx, __shfl_xor(mx, 8));
      float m_new = fmaxf(m_i[r], mx);
      float rs = 0.f;
#pragma unroll
      for (int t = 0; t < 4; ++t) {
        unsigned short pb = f2bf(__expf(Sv[t][r] - m_new));
        Ps[(wid * 16 + lg * 4 + r) * 64 + t * 16 + lr] = pb;
        rs += bf2f(pb);   // sum the rounded values so l matches the PV matmul
      }
      rs += __shfl_xor(rs, 1);
      rs += __shfl_xor(rs, 2);
      rs += __shfl_xor(rs, 4);
      rs += __shfl_xor(rs, 8);
      float alpha = __expf(m_i[r] - m_new);
      l_i[r] = l_i[r] * alpha + rs;
      m_i[r] = m_new;
#pragma unroll
      for (int t2 = 0; t2 < 4; ++t2) O[t2][r] *= alpha;
    }
    __syncthreads();

    // O += P @ V
#pragma unroll
    for (int t2 = 0; t2 < 4; ++t2) {
#pragma unroll
      for (int ks = 0; ks < 2; ++ks) {
        bf16x8 pa = *(const bf16x8*)&Ps[(wid * 16 + lr) * 64 + ks * 32 + lg * 8];
        bf16x8 vf = *(const bf16x8*)&VTs[(t2 * 16 + lr) * 72 + ks * 32 + lg * 8];
        O[t2] = __builtin_amdgcn_mfma_f32_16x16x32_bf16(pa, vf, O[t2], 0, 0, 0);
      }
    }
    __syncthreads();
  }

  // epilogue: AO[b, s, h*64+d] bf16 (merge heads)
#pragma unroll
  for (int t2 = 0; t2 < 4; ++t2) {
    int d = t2 * 16 + lr;
#pragma unroll
    for (int r = 0; r < 4; ++r) {
      int row = qt * 64 + wid * 16 + lg * 4 + r;
      float o = O[t2][r] / l_i[r];
      AO[((size_t)b * S_LEN + row) * D_MODEL + h * HDIM + d] = f2bf(o);
    }
  }
}

extern "C" void kernel_launch(void* const* d_in, const int* in_sizes, int n_in,
                              void* d_out, int out_size, void* d_ws, size_t ws_size,
                              hipStream_t stream) {
  const float* x      = (const float*)d_in[0];
  const float* w_attn = (const float*)d_in[1];
  const float* b_attn = (const float*)d_in[2];
  const float* w_proj = (const float*)d_in[3];
  const float* b_proj = (const float*)d_in[4];
  float* out = (float*)d_out;

  // ws layout (bf16 elements), total ~40 MB
  unsigned short* ws     = (unsigned short*)d_ws;
  unsigned short* xb     = ws;                                   // 4096x1024
  unsigned short* wqkvT  = xb + (size_t)M_ROWS * D_MODEL;        // 3072x1024
  unsigned short* wprojT = wqkvT + (size_t)N_QKV * D_MODEL;      // 1024x1024
  unsigned short* Qb     = wprojT + (size_t)D_MODEL * D_MODEL;   // [B,H,S,hd]
  unsigned short* Kb     = Qb + (size_t)M_ROWS * D_MODEL;
  unsigned short* Vb     = Kb + (size_t)M_ROWS * D_MODEL;
  unsigned short* AO     = xb;  // reuse: xb dead after QKV GEMM

  int n4 = M_ROWS * D_MODEL / 4;
  k_cast4<<<(n4 + 255) / 256, 256, 0, stream>>>(x, xb, n4);
  k_transcast<<<dim3(N_QKV / 32, D_MODEL / 32), 256, 0, stream>>>(w_attn, wqkvT, D_MODEL, N_QKV);
  k_transcast<<<dim3(D_MODEL / 32, D_MODEL / 32), 256, 0, stream>>>(w_proj, wprojT, D_MODEL, D_MODEL);
  k_gemm_qkv<<<dim3(N_QKV / 128, M_ROWS / 128), 256, 0, stream>>>(xb, wqkvT, b_attn, Qb, Kb, Vb);
  k_attn<<<dim3(S_LEN / 64, BATCH * NHEAD), 256, 0, stream>>>(Qb, Kb, Vb, AO);
  k_gemm_proj<<<dim3(D_MODEL / 128, M_ROWS / 128), 256, 0, stream>>>(AO, wprojT, b_proj, out);
}

// Round 2
// 276.628 us; speedup vs baseline: 1.3690x; 1.3690x over previous
//
#include <hip/hip_runtime.h>

#define S_LEN 2048
#define D_MODEL 1024
#define NHEAD 16
#define HDIM 64
#define BATCH 2
#define M_ROWS (BATCH * S_LEN)   // 4096
#define N_QKV (3 * D_MODEL)      // 3072

typedef __attribute__((ext_vector_type(8))) short bf16x8;
typedef __attribute__((ext_vector_type(4))) float f32x4;

static __device__ __forceinline__ unsigned short f2bf(float f) {
  unsigned int u = __float_as_uint(f);
  u += 0x7FFFu + ((u >> 16) & 1u);   // RNE
  return (unsigned short)(u >> 16);
}
// pack two floats to bf16x2 (round-half-up: +0x8000 then take hi16 via v_perm)
static __device__ __forceinline__ unsigned int pkbf(float a, float b) {
  unsigned int ua = __float_as_uint(a) + 0x8000u;
  unsigned int ub = __float_as_uint(b) + 0x8000u;
  return __builtin_amdgcn_perm(ub, ua, 0x07060302u);
}

// async global->LDS 16B copy (wave-uniform LDS base + lane*16 layout required)
static __device__ __forceinline__ void async_cp16(unsigned short* lds, const unsigned short* g) {
  __builtin_amdgcn_global_load_lds((__attribute__((address_space(1))) void*)g,
                                   (__attribute__((address_space(3))) void*)lds, 16, 0, 0);
}

// ---------------- cast fp32 -> bf16 (vectorized x4) ----------------
__global__ __launch_bounds__(256) void k_cast4(const float* __restrict__ x,
                                               unsigned short* __restrict__ y, int n4) {
  int i = blockIdx.x * 256 + threadIdx.x;
  if (i >= n4) return;
  float4 v = ((const float4*)x)[i];
  ushort4 o;
  o.x = f2bf(v.x); o.y = f2bf(v.y); o.z = f2bf(v.z); o.w = f2bf(v.w);
  ((ushort4*)y)[i] = o;
}

// ------------- transpose + cast: w[K][N] fp32 -> wT[N][K] bf16 -------------
__global__ __launch_bounds__(256) void k_transcast(const float* __restrict__ w,
                                                   unsigned short* __restrict__ wT,
                                                   int Kdim, int Ndim) {
  __shared__ unsigned short T[32][33];
  int n0 = blockIdx.x * 32, k0 = blockIdx.y * 32;
  int tx = threadIdx.x & 31, ty = threadIdx.x >> 5;
#pragma unroll
  for (int j = 0; j < 4; ++j) {
    int r = ty + j * 8;
    T[r][tx] = f2bf(w[(size_t)(k0 + r) * Ndim + n0 + tx]);
  }
  __syncthreads();
#pragma unroll
  for (int j = 0; j < 4; ++j) {
    int r = ty + j * 8;
    wT[(size_t)(n0 + r) * Kdim + k0 + tx] = T[tx][r];
  }
}

// ---------------- QKV GEMM: [4096,1024] x [1024,3072] + bias ----------------
// Q scaled by 0.125*log2(e) (softmax runs in exp2 domain); V written transposed.
__global__ __launch_bounds__(256) void k_gemm_qkv(const unsigned short* __restrict__ A,
                                                  const unsigned short* __restrict__ Bt,
                                                  const float* __restrict__ bias,
                                                  unsigned short* __restrict__ Qb,
                                                  unsigned short* __restrict__ Kbuf,
                                                  unsigned short* __restrict__ VTb) {
  __shared__ __align__(16) unsigned short As[128 * 32];
  __shared__ __align__(16) unsigned short Bs[128 * 32];
  const int tid = threadIdx.x;
  const int wid = tid >> 6, lane = tid & 63;
  const int lr = lane & 15, lg = lane >> 4;
  const int bm = blockIdx.y * 128, bn = blockIdx.x * 128;
  const int wm = (wid >> 1) * 64, wn = (wid & 1) * 64;
  const int K = D_MODEL;
  const int c0 = tid, c1 = tid + 256;   // 16B chunks: row = c>>2, kchunk = c&3
  const size_t a0o = (size_t)(bm + (c0 >> 2)) * K + (c0 & 3) * 8;
  const size_t a1o = (size_t)(bm + (c1 >> 2)) * K + (c1 & 3) * 8;
  const size_t b0o = (size_t)(bn + (c0 >> 2)) * K + (c0 & 3) * 8;
  const size_t b1o = (size_t)(bn + (c1 >> 2)) * K + (c1 & 3) * 8;

  f32x4 acc[4][4] = {};

  for (int k0 = 0; k0 < K; k0 += 32) {
    __syncthreads();
    async_cp16(&As[c0 * 8], &A[a0o + k0]);
    async_cp16(&As[c1 * 8], &A[a1o + k0]);
    async_cp16(&Bs[c0 * 8], &Bt[b0o + k0]);
    async_cp16(&Bs[c1 * 8], &Bt[b1o + k0]);
    __syncthreads();
    bf16x8 af[4], bfr[4];
#pragma unroll
    for (int i = 0; i < 4; ++i) af[i] = *(const bf16x8*)&As[(wm + i * 16 + lr) * 32 + lg * 8];
#pragma unroll
    for (int t = 0; t < 4; ++t) bfr[t] = *(const bf16x8*)&Bs[(wn + t * 16 + lr) * 32 + lg * 8];
#pragma unroll
    for (int i = 0; i < 4; ++i)
#pragma unroll
      for (int t = 0; t < 4; ++t)
        acc[i][t] = __builtin_amdgcn_mfma_f32_16x16x32_bf16(af[i], bfr[t], acc[i][t], 0, 0, 0);
  }
  // epilogue: Q (scaled), K row-major [bh][s][d]; V transposed [bh][d][s]
#pragma unroll
  for (int i = 0; i < 4; ++i) {
#pragma unroll
    for (int t = 0; t < 4; ++t) {
      int n = bn + wn + t * 16 + lr;
      int part = n >> 10, rem = n & 1023;
      int h = rem >> 6, d = rem & 63;
      float bv = bias[n];
      int row0 = bm + wm + i * 16 + lg * 4;
      int bb = row0 >> 11, s0 = row0 & 2047;   // 4 rows never cross batch boundary
      if (part == 2) {
        ushort4 vv;
        vv.x = f2bf(acc[i][t][0] + bv);
        vv.y = f2bf(acc[i][t][1] + bv);
        vv.z = f2bf(acc[i][t][2] + bv);
        vv.w = f2bf(acc[i][t][3] + bv);
        *(ushort4*)&VTb[(((size_t)(bb << 4) + h) * HDIM + d) * S_LEN + s0] = vv;
      } else {
        unsigned short* dst = (part == 0) ? Qb : Kbuf;
        float sc = (part == 0) ? 0.18033688011112042f : 1.0f;  // 0.125*log2(e)
#pragma unroll
        for (int r = 0; r < 4; ++r)
          dst[(((size_t)(bb << 4) + h) * S_LEN + (s0 + r)) * HDIM + d] = f2bf((acc[i][t][r] + bv) * sc);
      }
    }
  }
}

// ---------------- Proj GEMM: [4096,1024] x [1024,1024] + bias -> fp32 ----------------
__global__ __launch_bounds__(256) void k_gemm_proj(const unsigned short* __restrict__ A,
                                                   const unsigned short* __restrict__ Bt,
                                                   const float* __restrict__ bias,
                                                   float* __restrict__ out) {
  __shared__ __align__(16) unsigned short As[128 * 32];
  __shared__ __align__(16) unsigned short Bs[128 * 32];
  const int tid = threadIdx.x;
  const int wid = tid >> 6, lane = tid & 63;
  const int lr = lane & 15, lg = lane >> 4;
  const int bm = blockIdx.y * 128, bn = blockIdx.x * 128;
  const int wm = (wid >> 1) * 64, wn = (wid & 1) * 64;
  const int K = D_MODEL;
  const int c0 = tid, c1 = tid + 256;
  const size_t a0o = (size_t)(bm + (c0 >> 2)) * K + (c0 & 3) * 8;
  const size_t a1o = (size_t)(bm + (c1 >> 2)) * K + (c1 & 3) * 8;
  const size_t b0o = (size_t)(bn + (c0 >> 2)) * K + (c0 & 3) * 8;
  const size_t b1o = (size_t)(bn + (c1 >> 2)) * K + (c1 & 3) * 8;

  f32x4 acc[4][4] = {};

  for (int k0 = 0; k0 < K; k0 += 32) {
    __syncthreads();
    async_cp16(&As[c0 * 8], &A[a0o + k0]);
    async_cp16(&As[c1 * 8], &A[a1o + k0]);
    async_cp16(&Bs[c0 * 8], &Bt[b0o + k0]);
    async_cp16(&Bs[c1 * 8], &Bt[b1o + k0]);
    __syncthreads();
    bf16x8 af[4], bfr[4];
#pragma unroll
    for (int i = 0; i < 4; ++i) af[i] = *(const bf16x8*)&As[(wm + i * 16 + lr) * 32 + lg * 8];
#pragma unroll
    for (int t = 0; t < 4; ++t) bfr[t] = *(const bf16x8*)&Bs[(wn + t * 16 + lr) * 32 + lg * 8];
#pragma unroll
    for (int i = 0; i < 4; ++i)
#pragma unroll
      for (int t = 0; t < 4; ++t)
        acc[i][t] = __builtin_amdgcn_mfma_f32_16x16x32_bf16(af[i], bfr[t], acc[i][t], 0, 0, 0);
  }
#pragma unroll
  for (int i = 0; i < 4; ++i) {
#pragma unroll
    for (int t = 0; t < 4; ++t) {
      int n = bn + wn + t * 16 + lr;
      float bv = bias[n];
#pragma unroll
      for (int r = 0; r < 4; ++r) {
        int row = bm + wm + i * 16 + lg * 4 + r;
        out[(size_t)row * D_MODEL + n] = acc[i][t][r] + bv;
      }
    }
  }
}

// ---------------- Flash attention, wave-autonomous S^T/O^T scheme ----------------
// Block = 4 waves x 32 q-rows = 128 rows. No __syncthreads anywhere.
// S^T = mfma(A=K-rows, B=Q-rows): C[key=quad*4+r][q=lr]  (Q pre-scaled by 0.125*log2e)
// O^T = mfma(A=VT-rows, B=P-rows): C[d=quad*4+r][q=lr]; m/l/alpha indexed by q=lr.
__global__ __launch_bounds__(256, 2) void k_attn2(const unsigned short* __restrict__ Qb,
                                                  const unsigned short* __restrict__ Kb,
                                                  const unsigned short* __restrict__ VT,
                                                  unsigned short* __restrict__ AO) {
  const int qblk = (int)(gridDim.x - 1) - (int)blockIdx.x;  // heavy blocks first
  const int bh = blockIdx.y;
  const int tid = threadIdx.x;
  const int wid = tid >> 6, lane = tid & 63;
  const int lr = lane & 15, quad = lane >> 4;
  const int b = bh >> 4, h = bh & 15;
  const int base_q = qblk * 128 + wid * 32;

  __shared__ __align__(16) unsigned short Pbuf[4][16 * 72];  // per-wave P round-trip, pad 72
  unsigned short* pb = &Pbuf[wid][0];

  const unsigned short* Qp = Qb + ((size_t)bh * S_LEN + base_q) * HDIM;
  const unsigned short* Kbh = Kb + (size_t)bh * S_LEN * HDIM;
  const unsigned short* VTbh = VT + (size_t)bh * HDIM * S_LEN;

  bf16x8 qf[2][2];
#pragma unroll
  for (int st = 0; st < 2; ++st)
#pragma unroll
    for (int dh = 0; dh < 2; ++dh)
      qf[st][dh] = *(const bf16x8*)&Qp[(st * 16 + lr) * HDIM + dh * 32 + quad * 8];

  f32x4 Ot[2][4] = {};
  float m_s[2] = {-1e30f, -1e30f};
  float l_s[2] = {0.f, 0.f};

  const int ntile = ((base_q + 31) >> 6) + 1;
  for (int it = 0; it < ntile; ++it) {
    const int k0 = it * 64;
    bf16x8 kf[4][2], vf[4][2];
#pragma unroll
    for (int kg = 0; kg < 4; ++kg)
#pragma unroll
      for (int dh = 0; dh < 2; ++dh)
        kf[kg][dh] = *(const bf16x8*)&Kbh[(size_t)(k0 + kg * 16 + lr) * HDIM + dh * 32 + quad * 8];
#pragma unroll
    for (int dg = 0; dg < 4; ++dg)
#pragma unroll
      for (int kh = 0; kh < 2; ++kh)
        vf[dg][kh] = *(const bf16x8*)&VTbh[(size_t)(dg * 16 + lr) * S_LEN + k0 + kh * 32 + quad * 8];

#pragma unroll
    for (int st = 0; st < 2; ++st) {
      const int srow = base_q + st * 16;
      f32x4 Sv[4];
#pragma unroll
      for (int kg = 0; kg < 4; ++kg) {
        f32x4 a = {};
        a = __builtin_amdgcn_mfma_f32_16x16x32_bf16(kf[kg][0], qf[st][0], a, 0, 0, 0);
        a = __builtin_amdgcn_mfma_f32_16x16x32_bf16(kf[kg][1], qf[st][1], a, 0, 0, 0);
        Sv[kg] = a;
      }
      if (k0 + 63 > srow) {            // diagonal tile(s): apply causal mask
        const int q = srow + lr;
#pragma unroll
        for (int kg = 0; kg < 4; ++kg)
#pragma unroll
          for (int r = 0; r < 4; ++r)
            if (k0 + kg * 16 + quad * 4 + r > q) Sv[kg][r] = -1e30f;
      }
      float mx = m_s[st];
#pragma unroll
      for (int kg = 0; kg < 4; ++kg)
        mx = fmaxf(mx, fmaxf(fmaxf(Sv[kg][0], Sv[kg][1]), fmaxf(Sv[kg][2], Sv[kg][3])));
      mx = fmaxf(mx, __shfl_xor(mx, 16));
      mx = fmaxf(mx, __shfl_xor(mx, 32));
      const float alpha = __builtin_amdgcn_exp2f(m_s[st] - mx);
      float rs = 0.f;
      float p[4][4];
#pragma unroll
      for (int kg = 0; kg < 4; ++kg)
#pragma unroll
        for (int r = 0; r < 4; ++r) {
          p[kg][r] = __builtin_amdgcn_exp2f(Sv[kg][r] - mx);
          rs += p[kg][r];
        }
      rs += __shfl_xor(rs, 16);
      rs += __shfl_xor(rs, 32);
      l_s[st] = l_s[st] * alpha + rs;
      m_s[st] = mx;
#pragma unroll
      for (int dg = 0; dg < 4; ++dg)
#pragma unroll
        for (int r = 0; r < 4; ++r) Ot[st][dg][r] *= alpha;
      // P: C-layout -> B-operand layout via per-wave LDS (2-way conflicts only)
#pragma unroll
      for (int kg = 0; kg < 4; ++kg) {
        *(unsigned int*)&pb[lr * 72 + kg * 16 + quad * 4]     = pkbf(p[kg][0], p[kg][1]);
        *(unsigned int*)&pb[lr * 72 + kg * 16 + quad * 4 + 2] = pkbf(p[kg][2], p[kg][3]);
      }
      bf16x8 pf0 = *(const bf16x8*)&pb[lr * 72 + quad * 8];
      bf16x8 pf1 = *(const bf16x8*)&pb[lr * 72 + 32 + quad * 8];
#pragma unroll
      for (int dg = 0; dg < 4; ++dg) {
        Ot[st][dg] = __builtin_amdgcn_mfma_f32_16x16x32_bf16(vf[dg][0], pf0, Ot[st][dg], 0, 0, 0);
        Ot[st][dg] = __builtin_amdgcn_mfma_f32_16x16x32_bf16(vf[dg][1], pf1, Ot[st][dg], 0, 0, 0);
      }
    }
  }

  // epilogue: AO[b][s][h*64+d], O^T has (d=dg*16+quad*4+r, q=lr)
#pragma unroll
  for (int st = 0; st < 2; ++st) {
    const float rl = __builtin_amdgcn_rcpf(l_s[st]);
    const int s = base_q + st * 16 + lr;
#pragma unroll
    for (int dg = 0; dg < 4; ++dg) {
      const size_t o = ((size_t)b * S_LEN + s) * D_MODEL + h * 64 + dg * 16 + quad * 4;
      *(unsigned int*)&AO[o]     = pkbf(Ot[st][dg][0] * rl, Ot[st][dg][1] * rl);
      *(unsigned int*)&AO[o + 2] = pkbf(Ot[st][dg][2] * rl, Ot[st][dg][3] * rl);
    }
  }
}

extern "C" void kernel_launch(void* const* d_in, const int* in_sizes, int n_in,
                              void* d_out, int out_size, void* d_ws, size_t ws_size,
                              hipStream_t stream) {
  const float* x      = (const float*)d_in[0];
  const float* w_attn = (const float*)d_in[1];
  const float* b_attn = (const float*)d_in[2];
  const float* w_proj = (const float*)d_in[3];
  const float* b_proj = (const float*)d_in[4];
  float* out = (float*)d_out;

  unsigned short* ws     = (unsigned short*)d_ws;
  unsigned short* xb     = ws;                                   // 4096x1024
  unsigned short* wqkvT  = xb + (size_t)M_ROWS * D_MODEL;        // 3072x1024
  unsigned short* wprojT = wqkvT + (size_t)N_QKV * D_MODEL;      // 1024x1024
  unsigned short* Qb     = wprojT + (size_t)D_MODEL * D_MODEL;   // [B*H, S, hd] (Q pre-scaled)
  unsigned short* Kb     = Qb + (size_t)M_ROWS * D_MODEL;        // [B*H, S, hd]
  unsigned short* VT     = Kb + (size_t)M_ROWS * D_MODEL;        // [B*H, hd, S]
  unsigned short* AO     = xb;  // reuse: xb dead after QKV GEMM

  int n4 = M_ROWS * D_MODEL / 4;
  k_cast4<<<(n4 + 255) / 256, 256, 0, stream>>>(x, xb, n4);
  k_transcast<<<dim3(N_QKV / 32, D_MODEL / 32), 256, 0, stream>>>(w_attn, wqkvT, D_MODEL, N_QKV);
  k_transcast<<<dim3(D_MODEL / 32, D_MODEL / 32), 256, 0, stream>>>(w_proj, wprojT, D_MODEL, D_MODEL);
  k_gemm_qkv<<<dim3(N_QKV / 128, M_ROWS / 128), 256, 0, stream>>>(xb, wqkvT, b_attn, Qb, Kb, VT);
  k_attn2<<<dim3(S_LEN / 128, BATCH * NHEAD), 256, 0, stream>>>(Qb, Kb, VT, AO);
  k_gemm_proj<<<dim3(D_MODEL / 128, M_ROWS / 128), 256, 0, stream>>>(AO, wprojT, b_proj, out);
}